// Round 8
// baseline (45.889 us; speedup 1.0000x reference)
//
#include <hip/hip_runtime.h>

// YoloLoss — R8: occupancy fix. R6/R7's 1-wave blocks were capped by the
// HW concurrent-workgroup/CU limit (~16) at ~50% occupancy. Now:
//  * TPB=256 (4 waves/block) -> 8 blocks/CU = 32 waves/CU = 100% occupancy.
//  * LDS shrunk to box-part only (10 f32/cell, DMA'd via global_load_lds
//    width-4 with per-lane scatter source); pred's class part is read
//    DIRECTLY from global in the BCE's coalesced float2 pattern. The two
//    streams jointly cover each pred cache line exactly once.
//  * no atomics: per-block partial -> d_ws, tiny reduce kernel.
// Inputs: pred f32[NC,30], tbox f32[NC,4], tcls f32[NC,20], objmap i32[NC].
// Output: d_out[0] = scalar loss (f32).

constexpr int TPB = 256;        // cells per block == block size (4 waves)
constexpr float EPSV = 1e-10f;

__device__ __forceinline__ float clamp01(float v) {
    return fminf(fmaxf(v, 0.0f), 1.0f);
}

template <bool ATOMIC>
__global__ __launch_bounds__(TPB, 8) void yolo_part(
    const float* __restrict__ pred,
    const float* __restrict__ tbox,
    const float* __restrict__ tcls,
    const int* __restrict__ objmap,
    float* __restrict__ partial,     // ws path (ATOMIC=false)
    float* __restrict__ out,         // fallback path (ATOMIC=true)
    float inv_n)
{
    __shared__ float lds_box[TPB * 10];   // 10240 B: [cell][10] box part
    __shared__ float lds_obj[TPB];        //  1024 B
    __shared__ float wsum[4];

    const int t = threadIdx.x;
    const int wave = t >> 6;
    const int lane = t & 63;
    const size_t tile = blockIdx.x;
    const size_t cell0 = tile * TPB;

    // ---- 1) own-cell register loads (coalesced) ----
    const float4 tb = reinterpret_cast<const float4*>(tbox)[cell0 + t];
    const int ob = objmap[cell0 + t];

    // ---- 2) DMA box part -> LDS: 2560 dwords, linear LDS dest per wave,
    //         per-lane scatter source g(j) = 30*(j/10) + j%10 ----
    {
        const float* gp = pred + cell0 * 30;
        #pragma unroll
        for (int k = 0; k < 10; ++k) {
            const int j = k * 256 + wave * 64 + lane;
            const int c = j / 10;
            const int q = j - c * 10;
            const float* src = gp + c * 30 + q;
            float* ldst = lds_box + k * 256 + wave * 64;   // wave-uniform
            __builtin_amdgcn_global_load_lds(
                (const __attribute__((address_space(1))) void*)src,
                (__attribute__((address_space(3))) void*)ldst, 4, 0, 0);
        }
    }
    lds_obj[t] = ob ? 1.0f : 0.0f;
    __syncthreads();    // drains vmcnt (DMA + reg loads) and publishes LDS

    // ---- 3) per-cell box terms (own cell, float2 bursts from LDS) ----
    const float2* lb2 = reinterpret_cast<const float2*>(lds_box) + t * 5;
    const float2 b0 = lb2[0], b1 = lb2[1], b2 = lb2[2], b3 = lb2[3],
                 b4 = lb2[4];
    const float p0x = b0.x, p0y = b0.y, p0w = b1.x, p0h = b1.y, c0 = b2.x;
    const float p1x = b2.y, p1y = b3.x, p1w = b3.y, p1h = b4.x, c1 = b4.y;

    const float objf = ob ? 1.0f : 0.0f;
    const float tx = tb.x, ty = tb.y, tw = tb.z, th = tb.w;

    const float invS = 1.0f / 14.0f;
    const float tcx = tx * invS, tcy = ty * invS;
    const float tww = fmaxf(tw, EPSV), thh = fmaxf(th, EPSV);
    const float tx1 = clamp01(tcx - 0.5f * tww);
    const float ty1 = clamp01(tcy - 0.5f * thh);
    const float tx2 = clamp01(tcx + 0.5f * tww);
    const float ty2 = clamp01(tcy + 0.5f * thh);
    const float tarea = (tx2 - tx1) * (ty2 - ty1);

    float iou0, iou1;
    {
        const float cx = p0x * invS, cy = p0y * invS;
        const float ww = fmaxf(p0w, EPSV), hh = fmaxf(p0h, EPSV);
        const float x1 = clamp01(cx - 0.5f * ww), y1 = clamp01(cy - 0.5f * hh);
        const float x2 = clamp01(cx + 0.5f * ww), y2 = clamp01(cy + 0.5f * hh);
        const float lx = fmaxf(x1, tx1), ly = fmaxf(y1, ty1);
        const float rx = fminf(x2, tx2), ry = fminf(y2, ty2);
        const float inter = fmaxf(rx - lx, 0.0f) * fmaxf(ry - ly, 0.0f);
        const float pa = (x2 - x1) * (y2 - y1);
        iou0 = inter / (pa + tarea - inter + EPSV);
    }
    {
        const float cx = p1x * invS, cy = p1y * invS;
        const float ww = fmaxf(p1w, EPSV), hh = fmaxf(p1h, EPSV);
        const float x1 = clamp01(cx - 0.5f * ww), y1 = clamp01(cy - 0.5f * hh);
        const float x2 = clamp01(cx + 0.5f * ww), y2 = clamp01(cy + 0.5f * hh);
        const float lx = fmaxf(x1, tx1), ly = fmaxf(y1, ty1);
        const float rx = fminf(x2, tx2), ry = fminf(y2, ty2);
        const float inter = fmaxf(rx - lx, 0.0f) * fmaxf(ry - ly, 0.0f);
        const float pa = (x2 - x1) * (y2 - y1);
        iou1 = inter / (pa + tarea - inter + EPSV);
    }

    const float d0 = c0 - 0.05f, d1 = c1 - 0.05f;
    const float noobj = (d0 * d0 + d1 * d1) * (1.0f - objf);

    const bool sel = iou1 > iou0;                    // tie -> box 0
    const float biou = fminf((sel ? iou1 : iou0) + 0.5f, 0.95f);
    const float bx = sel ? p1x : p0x;
    const float by = sel ? p1y : p0y;
    const float bw = sel ? p1w : p0w;
    const float bh = sel ? p1h : p0h;
    const float bc = sel ? c1 : c0;

    const float spw = sqrtf(fabsf(bw) + 1e-6f);
    const float stw = sqrtf(fabsf(tw) + 1e-6f);
    const float sph = sqrtf(fabsf(bh) + 1e-6f);
    const float sth = sqrtf(fabsf(th) + 1e-6f);
    const float dx = bx - tx, dy = by - ty, dw = spw - stw, dh = sph - sth;
    const float reg = dx * dx + dy * dy + dw * dw + dh * dh;
    const float dcf = bc - biou;

    float acc = noobj * 0.5f + (reg * 10.0f + dcf * dcf * 10.0f) * objf;

    // ---- 4) class BCE: tcls coalesced float4; pred-cls DIRECT from global
    //         (2x aligned float2 per k, consecutive threads -> consecutive
    //         16B chunks). bce = -ln2*(lq + t*(lp-lq)). ----
    const float4* gtc4 = reinterpret_cast<const float4*>(tcls) + cell0 * 5;
    const float* gcls = pred + cell0 * 30;
    float csum = 0.0f;
    #pragma unroll
    for (int k = 0; k < 5; ++k) {
        const int j4 = t + k * 256;
        const int ci = j4 / 5;
        const int r  = j4 - ci * 5;
        const float4 tvv = gtc4[j4];
        const float2* pc2 =
            reinterpret_cast<const float2*>(gcls + ci * 30 + 10 + 4 * r);
        const float2 pa2 = pc2[0];
        const float2 pb2 = pc2[1];
        const float of = lds_obj[ci];
        const float pv[4] = {pa2.x, pa2.y, pb2.x, pb2.y};
        const float tvf[4] = {tvv.x, tvv.y, tvv.z, tvv.w};
        float s = 0.0f;
        #pragma unroll
        for (int u = 0; u < 4; ++u) {
            const float p = fminf(fmaxf(pv[u], 1e-7f), 1.0f - 1e-7f);
            const float lp = __log2f(p);
            const float lq = __log2f(1.0f - p);
            s += lq + tvf[u] * (lp - lq);
        }
        csum += s * of;
    }
    acc += csum * (-0.5f * 0.69314718055994530942f);

    // ---- 5) reduce: wave shfl -> LDS -> one plain store per block ----
    #pragma unroll
    for (int off = 32; off > 0; off >>= 1) acc += __shfl_down(acc, off);
    if (lane == 0) wsum[wave] = acc;
    __syncthreads();
    if (t == 0) {
        const float blocksum = wsum[0] + wsum[1] + wsum[2] + wsum[3];
        if (ATOMIC) atomicAdd(out, blocksum * inv_n);
        else partial[tile] = blocksum;
    }
}

__global__ __launch_bounds__(1024) void yolo_reduce(
    const float* __restrict__ partial, float* __restrict__ out,
    int nblk4, float inv_n)
{
    __shared__ float ws[16];
    const int t = threadIdx.x;
    const float4* p4 = reinterpret_cast<const float4*>(partial);
    float s = 0.0f;
    for (int i = t; i < nblk4; i += 1024) {
        const float4 v = p4[i];
        s += (v.x + v.y) + (v.z + v.w);
    }
    #pragma unroll
    for (int off = 32; off > 0; off >>= 1) s += __shfl_down(s, off);
    if ((t & 63) == 0) ws[t >> 6] = s;
    __syncthreads();
    if (t < 16) {
        s = ws[t];
        #pragma unroll
        for (int off = 8; off > 0; off >>= 1) s += __shfl_down(s, off, 16);
        if (t == 0) out[0] = s * inv_n;
    }
}

extern "C" void kernel_launch(void* const* d_in, const int* in_sizes, int n_in,
                              void* d_out, int out_size, void* d_ws, size_t ws_size,
                              hipStream_t stream) {
    const float* pred = (const float*)d_in[0];
    const float* tbox = (const float*)d_in[1];
    const float* tcls = (const float*)d_in[2];
    const int* objmap = (const int*)d_in[3];
    float* out = (float*)d_out;

    const int ncells = in_sizes[3];          // N * S * S (802816)
    const int n_imgs = ncells / 196;         // N (4096)
    const float inv_n = 1.0f / (float)n_imgs;
    const int nblk = ncells / TPB;           // 3136, exact

    if (ws_size >= (size_t)nblk * sizeof(float)) {
        float* partial = (float*)d_ws;
        yolo_part<false><<<nblk, TPB, 0, stream>>>(pred, tbox, tcls, objmap,
                                                   partial, nullptr, inv_n);
        yolo_reduce<<<1, 1024, 0, stream>>>(partial, out, nblk / 4, inv_n);
    } else {
        // fallback if workspace too small: atomic accumulate (zero out first)
        hipMemsetAsync(out, 0, sizeof(float), stream);
        yolo_part<true><<<nblk, TPB, 0, stream>>>(pred, tbox, tcls, objmap,
                                                  nullptr, out, inv_n);
    }
}

// Round 9
// 34.693 us; speedup vs baseline: 1.3227x; 1.3227x over previous
//
#include <hip/hip_runtime.h>

// YoloLoss — R9: R7 structure (unified single-pass pred staging via LDS-DMA,
// no atomics, ws+reduce) with TPB=128 (2-wave blocks) to get past the
// ~16-workgroup/CU cap that froze 1-wave blocks at ~16 waves/CU.
// LDS 15.9KB -> 10 blocks/CU x 2 waves = 20 waves/CU.
// Inputs: pred f32[NC,30], tbox f32[NC,4], tcls f32[NC,20], objmap i32[NC].
// Output: d_out[0] = scalar loss (f32).

constexpr int TPB = 128;        // cells per block == block size (2 waves)
constexpr float EPSV = 1e-10f;

__device__ __forceinline__ float clamp01(float v) {
    return fminf(fmaxf(v, 0.0f), 1.0f);
}

// async global->LDS, 16B per active lane; LDS dst = wave-uniform base + lane*16
__device__ __forceinline__ void gl_lds16(const float4* g, float4* lds_base) {
    __builtin_amdgcn_global_load_lds(
        (const __attribute__((address_space(1))) void*)g,
        (__attribute__((address_space(3))) void*)lds_base, 16, 0, 0);
}

template <bool ATOMIC>
__global__ __launch_bounds__(TPB, 5) void yolo_part(
    const float* __restrict__ pred,
    const float* __restrict__ tbox,
    const float* __restrict__ tcls,
    const int* __restrict__ objmap,
    float* __restrict__ partial,     // ws path (ATOMIC=false)
    float* __restrict__ out,         // fallback path (ATOMIC=true)
    float inv_n)
{
    __shared__ float4 lds_p4[TPB * 15 / 2];   // 960 float4 = 15360 B
    __shared__ float lds_obj[TPB];            //   512 B
    __shared__ float wsum[2];

    const int t = threadIdx.x;
    const int wave = t >> 6;
    const int lane = t & 63;
    const size_t tile = blockIdx.x;
    const size_t cell0 = tile * TPB;

    // ---- 1) current-tile register loads (oldest in vmcnt queue) ----
    const float4 tb = reinterpret_cast<const float4*>(tbox)[cell0 + t];
    float4 tv[5];                                    // tcls, coalesced j4 order
    {
        const float4* gtc4 = reinterpret_cast<const float4*>(tcls) + cell0 * 5;
        #pragma unroll
        for (int k = 0; k < 5; ++k) tv[k] = gtc4[t + k * TPB];
    }
    const int ob = objmap[cell0 + t];

    // ---- 2) pred tile -> LDS via async DMA (960 float4, 480 per wave:
    //         7 full-wave chunks + one 32-lane chunk) ----
    {
        const float4* gp4 = reinterpret_cast<const float4*>(pred) +
                            tile * (TPB * 30 / 4);
        const int wbase = wave * 480;
        #pragma unroll
        for (int k = 0; k < 7; ++k)
            gl_lds16(gp4 + wbase + k * 64 + lane, lds_p4 + wbase + k * 64);
        if (lane < 32)
            gl_lds16(gp4 + wbase + 448 + lane, lds_p4 + wbase + 448);
    }
    lds_obj[t] = ob ? 1.0f : 0.0f;
    __syncthreads();     // drains DMA vmcnt, publishes LDS across both waves

    const float2* lds2 = reinterpret_cast<const float2*>(lds_p4);
    const float objf = ob ? 1.0f : 0.0f;

    // ---- 3) burst-load own-cell box part (10 floats as 5 float2) ----
    float2 pb[5];
    #pragma unroll
    for (int q = 0; q < 5; ++q) pb[q] = lds2[t * 15 + q];

    // ---- 3b) burst-load cross-cell BCE operands (20 floats as 10 float2) ----
    float2 pcl[10];
    int cis[5];
    #pragma unroll
    for (int k = 0; k < 5; ++k) {
        const int j4 = t + k * TPB;
        const int ci = j4 / 5;
        const int r  = j4 - ci * 5;
        cis[k] = ci;
        const int b2 = ci * 15 + 5 + 2 * r;   // (ci*30 + 10 + 4r)/2, 8B-aligned
        pcl[2 * k]     = lds2[b2];
        pcl[2 * k + 1] = lds2[b2 + 1];
    }

    // ---- 4) per-cell box terms (all operands in registers) ----
    const float tx = tb.x, ty = tb.y, tw = tb.z, th = tb.w;
    const float invS = 1.0f / 14.0f;
    const float tcx = tx * invS, tcy = ty * invS;
    const float tww = fmaxf(tw, EPSV), thh = fmaxf(th, EPSV);
    const float tx1 = clamp01(tcx - 0.5f * tww);
    const float ty1 = clamp01(tcy - 0.5f * thh);
    const float tx2 = clamp01(tcx + 0.5f * tww);
    const float ty2 = clamp01(tcy + 0.5f * thh);
    const float tarea = (tx2 - tx1) * (ty2 - ty1);

    const float p0x = pb[0].x, p0y = pb[0].y, p0w = pb[1].x, p0h = pb[1].y;
    const float c0  = pb[2].x;
    const float p1x = pb[2].y, p1y = pb[3].x, p1w = pb[3].y, p1h = pb[4].x;
    const float c1  = pb[4].y;

    float iou0, iou1;
    {
        const float cx = p0x * invS, cy = p0y * invS;
        const float ww = fmaxf(p0w, EPSV), hh = fmaxf(p0h, EPSV);
        const float x1 = clamp01(cx - 0.5f * ww), y1 = clamp01(cy - 0.5f * hh);
        const float x2 = clamp01(cx + 0.5f * ww), y2 = clamp01(cy + 0.5f * hh);
        const float lx = fmaxf(x1, tx1), ly = fmaxf(y1, ty1);
        const float rx = fminf(x2, tx2), ry = fminf(y2, ty2);
        const float inter = fmaxf(rx - lx, 0.0f) * fmaxf(ry - ly, 0.0f);
        const float pa = (x2 - x1) * (y2 - y1);
        iou0 = inter / (pa + tarea - inter + EPSV);
    }
    {
        const float cx = p1x * invS, cy = p1y * invS;
        const float ww = fmaxf(p1w, EPSV), hh = fmaxf(p1h, EPSV);
        const float x1 = clamp01(cx - 0.5f * ww), y1 = clamp01(cy - 0.5f * hh);
        const float x2 = clamp01(cx + 0.5f * ww), y2 = clamp01(cy + 0.5f * hh);
        const float lx = fmaxf(x1, tx1), ly = fmaxf(y1, ty1);
        const float rx = fminf(x2, tx2), ry = fminf(y2, ty2);
        const float inter = fmaxf(rx - lx, 0.0f) * fmaxf(ry - ly, 0.0f);
        const float pa = (x2 - x1) * (y2 - y1);
        iou1 = inter / (pa + tarea - inter + EPSV);
    }

    const float d0 = c0 - 0.05f, d1 = c1 - 0.05f;
    const float noobj = (d0 * d0 + d1 * d1) * (1.0f - objf);

    const bool sel = iou1 > iou0;                    // tie -> box 0
    const float biou = fminf((sel ? iou1 : iou0) + 0.5f, 0.95f);
    const float bx = sel ? p1x : p0x;
    const float by = sel ? p1y : p0y;
    const float bw = sel ? p1w : p0w;
    const float bh = sel ? p1h : p0h;
    const float bc = sel ? c1 : c0;

    const float spw = sqrtf(fabsf(bw) + 1e-6f);
    const float stw = sqrtf(fabsf(tw) + 1e-6f);
    const float sph = sqrtf(fabsf(bh) + 1e-6f);
    const float sth = sqrtf(fabsf(th) + 1e-6f);
    const float dx = bx - tx, dy = by - ty, dw = spw - stw, dh = sph - sth;
    const float reg = dx * dx + dy * dy + dw * dw + dh * dh;
    const float dcf = bc - biou;

    float acc = noobj * 0.5f + (reg * 10.0f + dcf * dcf * 10.0f) * objf;

    // ---- 5) class BCE from registers: -ln2*(lq + t*(lp-lq)) ----
    float csum = 0.0f;
    #pragma unroll
    for (int k = 0; k < 5; ++k) {
        const float of = lds_obj[cis[k]];
        const float pv[4] = {pcl[2 * k].x, pcl[2 * k].y,
                             pcl[2 * k + 1].x, pcl[2 * k + 1].y};
        const float tvv[4] = {tv[k].x, tv[k].y, tv[k].z, tv[k].w};
        float s = 0.0f;
        #pragma unroll
        for (int u = 0; u < 4; ++u) {
            const float p = fminf(fmaxf(pv[u], 1e-7f), 1.0f - 1e-7f);
            const float lp = __log2f(p);
            const float lq = __log2f(1.0f - p);
            s += lq + tvv[u] * (lp - lq);
        }
        csum += s * of;
    }
    acc += csum * (-0.5f * 0.69314718055994530942f);

    // ---- 6) reduce: wave shfl -> LDS -> one plain store per block ----
    #pragma unroll
    for (int off = 32; off > 0; off >>= 1) acc += __shfl_down(acc, off);
    if (lane == 0) wsum[wave] = acc;
    __syncthreads();
    if (t == 0) {
        const float blocksum = wsum[0] + wsum[1];
        if (ATOMIC) atomicAdd(out, blocksum * inv_n);
        else partial[tile] = blocksum;
    }
}

__global__ __launch_bounds__(1024) void yolo_reduce(
    const float* __restrict__ partial, float* __restrict__ out,
    int nblk4, float inv_n)
{
    __shared__ float ws[16];
    const int t = threadIdx.x;
    const float4* p4 = reinterpret_cast<const float4*>(partial);
    float s = 0.0f;
    for (int i = t; i < nblk4; i += 1024) {
        const float4 v = p4[i];
        s += (v.x + v.y) + (v.z + v.w);
    }
    #pragma unroll
    for (int off = 32; off > 0; off >>= 1) s += __shfl_down(s, off);
    if ((t & 63) == 0) ws[t >> 6] = s;
    __syncthreads();
    if (t < 16) {
        s = ws[t];
        #pragma unroll
        for (int off = 8; off > 0; off >>= 1) s += __shfl_down(s, off, 16);
        if (t == 0) out[0] = s * inv_n;
    }
}

extern "C" void kernel_launch(void* const* d_in, const int* in_sizes, int n_in,
                              void* d_out, int out_size, void* d_ws, size_t ws_size,
                              hipStream_t stream) {
    const float* pred = (const float*)d_in[0];
    const float* tbox = (const float*)d_in[1];
    const float* tcls = (const float*)d_in[2];
    const int* objmap = (const int*)d_in[3];
    float* out = (float*)d_out;

    const int ncells = in_sizes[3];          // N * S * S (802816)
    const int n_imgs = ncells / 196;         // N (4096)
    const float inv_n = 1.0f / (float)n_imgs;
    const int nblk = ncells / TPB;           // 6272, exact

    if (ws_size >= (size_t)nblk * sizeof(float)) {
        float* partial = (float*)d_ws;
        yolo_part<false><<<nblk, TPB, 0, stream>>>(pred, tbox, tcls, objmap,
                                                   partial, nullptr, inv_n);
        yolo_reduce<<<1, 1024, 0, stream>>>(partial, out, nblk / 4, inv_n);
    } else {
        // fallback if workspace too small: atomic accumulate (zero out first)
        hipMemsetAsync(out, 0, sizeof(float), stream);
        yolo_part<true><<<nblk, TPB, 0, stream>>>(pred, tbox, tcls, objmap,
                                                  nullptr, out, inv_n);
    }
}